// Round 3
// baseline (144.817 us; speedup 1.0000x reference)
//
#include <hip/hip_runtime.h>

// ChoopyLoss: loss = -(1/B) * sum_{i,j} out[i,j] * r[i,j]
// where r[i,j] = 2*cum[i,j] / (j+1 + total_i)   (exact simplification of F1)
// B=2048, N=8192.

#define BLOCK 256
#define NROW 8192
#define PASSES 8   // NROW / (BLOCK*4)

__global__ __launch_bounds__(BLOCK) void f1_row_kernel(
    const float* __restrict__ outv,
    const int* __restrict__ labels,
    float* __restrict__ partials)
{
    const int row  = blockIdx.x;
    const int t    = threadIdx.x;
    const int lane = t & 63;
    const int wid  = t >> 6;

    const long long rowbase = (long long)row * NROW;
    const int*   lab = labels + rowbase;
    const float* op  = outv  + rowbase;

    __shared__ int wave_tot[PASSES][4];

    unsigned int mask = 0;       // 4 label bits per pass
    int incl[PASSES];            // inclusive wave-scan of per-thread 4-sums
    int sloc[PASSES];            // per-thread 4-sum

    // Phase 1: load labels (coalesced int4), pack bits, wave-scan per pass.
    #pragma unroll
    for (int p = 0; p < PASSES; ++p) {
        const int4 lv = *(const int4*)(lab + p * 1024 + t * 4);
        const int b0 = (lv.x != 0), b1 = (lv.y != 0), b2 = (lv.z != 0), b3 = (lv.w != 0);
        mask |= (unsigned)(b0 | (b1 << 1) | (b2 << 2) | (b3 << 3)) << (p * 4);
        const int s = b0 + b1 + b2 + b3;
        sloc[p] = s;
        int x = s;
        #pragma unroll
        for (int off = 1; off < 64; off <<= 1) {
            const int v = __shfl_up(x, off, 64);
            if (lane >= off) x += v;
        }
        incl[p] = x;
        if (lane == 63) wave_tot[p][wid] = x;
    }
    __syncthreads();

    // Cross-wave / cross-pass bases and row total (all threads read all 32 totals).
    int base[PASSES];
    int run = 0;
    #pragma unroll
    for (int p = 0; p < PASSES; ++p) {
        const int w0 = wave_tot[p][0], w1 = wave_tot[p][1],
                  w2 = wave_tot[p][2], w3 = wave_tot[p][3];
        const int wb = (wid > 0 ? w0 : 0) + (wid > 1 ? w1 : 0) + (wid > 2 ? w2 : 0);
        base[p] = run + wb + (incl[p] - sloc[p]);   // exclusive count before this thread's 4 elems
        run += w0 + w1 + w2 + w3;
    }
    const float ftot = (float)run;                  // row total (0 handled: cum==0 -> term 0)

    // Phase 2: load output (coalesced float4), accumulate out * 2*cum/(k+total).
    float acc = 0.f;
    #pragma unroll
    for (int p = 0; p < PASSES; ++p) {
        const float4 ov = *(const float4*)(op + p * 1024 + t * 4);
        int c = base[p];
        const int kbase = p * 1024 + t * 4;         // element index; k = kbase + l + 1
        const unsigned nib = (mask >> (p * 4)) & 0xFu;
        c += (nib & 1u);
        acc += ov.x * ((2.f * (float)c) / ((float)(kbase + 1) + ftot));
        c += (nib >> 1) & 1u;
        acc += ov.y * ((2.f * (float)c) / ((float)(kbase + 2) + ftot));
        c += (nib >> 2) & 1u;
        acc += ov.z * ((2.f * (float)c) / ((float)(kbase + 3) + ftot));
        c += (nib >> 3) & 1u;
        acc += ov.w * ((2.f * (float)c) / ((float)(kbase + 4) + ftot));
    }

    // Block reduction of acc (wave shuffle + LDS across 4 waves).
    #pragma unroll
    for (int off = 32; off > 0; off >>= 1) acc += __shfl_down(acc, off, 64);
    __shared__ float wacc[4];
    if (lane == 0) wacc[wid] = acc;
    __syncthreads();
    if (t == 0) partials[row] = wacc[0] + wacc[1] + wacc[2] + wacc[3];
}

__global__ __launch_bounds__(256) void f1_finalize_kernel(
    const float* __restrict__ partials, float* __restrict__ out, int B)
{
    double s = 0.0;
    for (int i = threadIdx.x; i < B; i += 256) s += (double)partials[i];
    #pragma unroll
    for (int off = 32; off > 0; off >>= 1) s += __shfl_down(s, off, 64);
    __shared__ double ws[4];
    const int lane = threadIdx.x & 63, wid = threadIdx.x >> 6;
    if (lane == 0) ws[wid] = s;
    __syncthreads();
    if (threadIdx.x == 0) {
        out[0] = (float)(-(ws[0] + ws[1] + ws[2] + ws[3]) / (double)B);
    }
}

extern "C" void kernel_launch(void* const* d_in, const int* in_sizes, int n_in,
                              void* d_out, int out_size, void* d_ws, size_t ws_size,
                              hipStream_t stream) {
    const float* outv   = (const float*)d_in[0];   // [B, N, 1] f32
    const int*   labels = (const int*)d_in[1];     // [B, N] i32
    float* partials = (float*)d_ws;                // B floats of scratch
    float* result   = (float*)d_out;

    const int B = 2048;
    f1_row_kernel<<<B, BLOCK, 0, stream>>>(outv, labels, partials);
    f1_finalize_kernel<<<1, 256, 0, stream>>>(partials, result, B);
}